// Round 4
// baseline (469.512 us; speedup 1.0000x reference)
//
#include <hip/hip_runtime.h>
#include <hip/hip_bf16.h>
#include <cstdint>
#include <cstddef>

#define B_   2
#define N_   2048
#define D_   2048
#define H_   16
#define HD_  128
#define C_   128
#define NC_  16
#define M_   4096   // B_*N_
#define QKVG_ 8192  // fused projection width: q|k|v|gate (v section left unwritten)

typedef __attribute__((ext_vector_type(8))) short bf16x8;
typedef __attribute__((ext_vector_type(4))) float f32x4;
typedef __attribute__((ext_vector_type(16))) float f32x16;

__device__ __forceinline__ uint16_t f2bf(float f){
  __hip_bfloat16 h = __float2bfloat16(f);
  return *reinterpret_cast<uint16_t*>(&h);
}
__device__ __forceinline__ float bf2f(uint16_t u){
  union { uint32_t i; float f; } v; v.i = ((uint32_t)u) << 16; return v.f;
}

__device__ __forceinline__ void async16(const uint16_t* g, uint16_t* l){
  __builtin_amdgcn_global_load_lds(
      (const __attribute__((address_space(1))) void*)g,
      (__attribute__((address_space(3))) void*)l, 16, 0, 0);
}

// [128][128] LDS tile swizzle (Ps in attn)
__device__ __forceinline__ int swz(int row, int c){
  return row*128 + ((((c >> 3) ^ row) & 15) << 3) + (c & 7);
}

// ---------------------------------------- all prep in ONE launch (grid.z)
// z=0..2: Wq/Wk/Wv -> WT slices; z=3: Wo->WoT; z=4: Wg2->Wg2T (by<4);
// z=5: Wg1 straight cast (bx<4); z=6,7: x straight cast (two row-halves).
__global__ __launch_bounds__(256)
void prep_all(const float* __restrict__ Wq, const float* __restrict__ Wk,
              const float* __restrict__ Wv, const float* __restrict__ Wo,
              const float* __restrict__ Wg2, const float* __restrict__ Wg1,
              const float* __restrict__ x,
              uint16_t* __restrict__ WT, uint16_t* __restrict__ WoT,
              uint16_t* __restrict__ Wg2T, uint16_t* __restrict__ Wg1b,
              uint16_t* __restrict__ xb)
{
  const int z = blockIdx.z;
  const int tx = threadIdx.x & 31;
  const int ty = threadIdx.x >> 5;   // 0..7
  __shared__ uint16_t tile[32][33];

  if (z >= 6){                       // straight cast x
    const int r0 = (z-6)*2048 + blockIdx.y*32, c0 = blockIdx.x*32;
    #pragma unroll
    for (int rr = 0; rr < 4; ++rr){
      int r = r0 + ty + rr*8;
      xb[(size_t)r*D_ + c0 + tx] = f2bf(x[(size_t)r*D_ + c0 + tx]);
    }
    return;
  }
  if (z == 5){                       // straight cast Wg1
    if (blockIdx.x >= 4) return;
    const int r0 = blockIdx.y*32, c0 = blockIdx.x*32;
    #pragma unroll
    for (int rr = 0; rr < 4; ++rr){
      int r = r0 + ty + rr*8;
      Wg1b[(size_t)r*HD_ + c0 + tx] = f2bf(Wg1[(size_t)r*HD_ + c0 + tx]);
    }
    return;
  }

  const float* src; uint16_t* dst; int R, Cc;
  if (z < 3)      { src = (z==0)?Wq:(z==1)?Wk:Wv; dst = WT + (size_t)z*D_*D_; R = D_; Cc = D_; }
  else if (z == 3){ src = Wo;  dst = WoT;  R = D_;  Cc = D_; }
  else            { if (blockIdx.y >= 4) return;
                    src = Wg2; dst = Wg2T; R = HD_; Cc = D_; }

  const int r0 = blockIdx.y*32, c0 = blockIdx.x*32;
  #pragma unroll
  for (int rr = 0; rr < 4; ++rr){
    int r = ty + rr*8;
    tile[r][tx] = f2bf(src[(size_t)(r0 + r)*Cc + c0 + tx]);
  }
  __syncthreads();
  #pragma unroll
  for (int rr = 0; rr < 4; ++rr){
    int r = ty + rr*8;
    dst[(size_t)(c0 + r)*R + r0 + tx] = tile[tx][r];
  }
}

// ------------------------------------------------- generic GEMM: BK=64, 32x32x16
// C = act(A @ Bt^T). blockIdx.z = split-K slice (fp32 partials for OUTBF=0).
template<int ACT, int OUTBF>
__global__ __launch_bounds__(256)
void gemm_bt2(const uint16_t* __restrict__ A, const uint16_t* __restrict__ Bt,
              void* __restrict__ Cout, int M, int Ncols, int K, int klen)
{
  __shared__ __align__(16) uint16_t As[128*64];
  __shared__ __align__(16) uint16_t Bs[128*64];
  const int t    = threadIdx.x;
  const int lane = t & 63, wave = t >> 6;
  const int wm = wave >> 1, wn = wave & 1;
  const int row0 = wm*64, col0 = wn*64;
  const int lm = lane & 31, lh = lane >> 5;

  const uint16_t* Ap = A  + (size_t)(blockIdx.y*128)*K;
  const uint16_t* Bp = Bt + (size_t)(blockIdx.x*128)*K;
  const int kbeg = blockIdx.z * klen;

  f32x16 acc[2][2];
  #pragma unroll
  for (int i = 0; i < 2; ++i)
    #pragma unroll
    for (int j = 0; j < 2; ++j)
      #pragma unroll
      for (int r = 0; r < 16; ++r) acc[i][j][r] = 0.f;

  const int srow = t >> 3;
  const int gch  = (t & 7) ^ (srow & 7);
  const size_t aoff0 = (size_t)srow*K + gch*8;

  for (int k0 = kbeg; k0 < kbeg + klen; k0 += 64){
    #pragma unroll
    for (int c = 0; c < 4; ++c){
      async16(Ap + (size_t)(c*32)*K + aoff0 + k0, As + c*2048 + t*8);
      async16(Bp + (size_t)(c*32)*K + aoff0 + k0, Bs + c*2048 + t*8);
    }
    __syncthreads();
    #pragma unroll
    for (int kh = 0; kh < 4; ++kh){
      bf16x8 af[2], bfr[2];
      const int ch = kh*2 + lh;
      #pragma unroll
      for (int i = 0; i < 2; ++i){
        int r = row0 + i*32 + lm;
        af[i] = *(const bf16x8*)(As + r*64 + ((ch ^ (r & 7)) << 3));
      }
      #pragma unroll
      for (int j = 0; j < 2; ++j){
        int r = col0 + j*32 + lm;
        bfr[j] = *(const bf16x8*)(Bs + r*64 + ((ch ^ (r & 7)) << 3));
      }
      #pragma unroll
      for (int i = 0; i < 2; ++i)
        #pragma unroll
        for (int j = 0; j < 2; ++j)
          acc[i][j] = __builtin_amdgcn_mfma_f32_32x32x16_bf16(af[i], bfr[j], acc[i][j], 0, 0, 0);
    }
    __syncthreads();
  }

  uint16_t* outb = (uint16_t*)Cout;
  float*    outf = (float*)Cout + (OUTBF ? 0 : (size_t)blockIdx.z*M*Ncols);
  #pragma unroll
  for (int i = 0; i < 2; ++i){
    #pragma unroll
    for (int j = 0; j < 2; ++j){
      #pragma unroll
      for (int r = 0; r < 16; ++r){
        int row = blockIdx.y*128 + row0 + i*32 + (r & 3) + 8*(r >> 2) + 4*lh;
        int col = blockIdx.x*128 + col0 + j*32 + lm;
        float v = acc[i][j][r];
        if (ACT == 1)      v = v / (1.f + __expf(-v));
        else if (ACT == 2) v = 1.f / (1.f + __expf(-v));
        size_t off = (size_t)row*Ncols + col;
        if (OUTBF) outb[off] = f2bf(v);
        else       outf[off] = v;
      }
    }
  }
}

// ------------------------------------- fused q|k|v|gate projection, special epilogue
// sections (blockIdx.x>>4): 0=q (natural, silu), 1=k (natural silu + dk-prescaled
// transpose kTs), 2=v (ONLY transposed vTg, silu), 3=gate (natural, sigmoid).
// Each v/k block covers exactly one (b,h,ic) 128x128 tile -> transposed scatter
// stores are merged by L2 (block fully covers the 32KB contiguous tile).
__global__ __launch_bounds__(256)
void gemm_qkvg(const uint16_t* __restrict__ A, const uint16_t* __restrict__ Bt,
               uint16_t* __restrict__ qkvg, uint16_t* __restrict__ vTg,
               uint16_t* __restrict__ kTs, const float* __restrict__ log_decay)
{
  const int K = D_;
  __shared__ __align__(16) uint16_t As[128*64];
  __shared__ __align__(16) uint16_t Bs[128*64];
  const int t    = threadIdx.x;
  const int lane = t & 63, wave = t >> 6;
  const int wm = wave >> 1, wn = wave & 1;
  const int row0 = wm*64, col0 = wn*64;
  const int lm = lane & 31, lh = lane >> 5;

  const uint16_t* Ap = A  + (size_t)(blockIdx.y*128)*K;
  const uint16_t* Bp = Bt + (size_t)(blockIdx.x*128)*K;

  f32x16 acc[2][2];
  #pragma unroll
  for (int i = 0; i < 2; ++i)
    #pragma unroll
    for (int j = 0; j < 2; ++j)
      #pragma unroll
      for (int r = 0; r < 16; ++r) acc[i][j][r] = 0.f;

  const int srow = t >> 3;
  const int gch  = (t & 7) ^ (srow & 7);
  const size_t aoff0 = (size_t)srow*K + gch*8;

  for (int k0 = 0; k0 < K; k0 += 64){
    #pragma unroll
    for (int c = 0; c < 4; ++c){
      async16(Ap + (size_t)(c*32)*K + aoff0 + k0, As + c*2048 + t*8);
      async16(Bp + (size_t)(c*32)*K + aoff0 + k0, Bs + c*2048 + t*8);
    }
    __syncthreads();
    #pragma unroll
    for (int kh = 0; kh < 4; ++kh){
      bf16x8 af[2], bfr[2];
      const int ch = kh*2 + lh;
      #pragma unroll
      for (int i = 0; i < 2; ++i){
        int r = row0 + i*32 + lm;
        af[i] = *(const bf16x8*)(As + r*64 + ((ch ^ (r & 7)) << 3));
      }
      #pragma unroll
      for (int j = 0; j < 2; ++j){
        int r = col0 + j*32 + lm;
        bfr[j] = *(const bf16x8*)(Bs + r*64 + ((ch ^ (r & 7)) << 3));
      }
      #pragma unroll
      for (int i = 0; i < 2; ++i)
        #pragma unroll
        for (int j = 0; j < 2; ++j)
          acc[i][j] = __builtin_amdgcn_mfma_f32_32x32x16_bf16(af[i], bfr[j], acc[i][j], 0, 0, 0);
    }
    __syncthreads();
  }

  const int sec = blockIdx.x >> 4;        // 0 q, 1 k, 2 v, 3 gate
  const int h   = blockIdx.x & 15;
  const int bb  = blockIdx.y >> 4;
  const int ic  = blockIdx.y & 15;
  const float ld = log_decay[h];
  uint16_t* tdst = (sec == 2 ? vTg : kTs) +
                   (((size_t)bb*H_ + h)*NC_ + ic)*(size_t)(HD_*C_);
  #pragma unroll
  for (int i = 0; i < 2; ++i){
    #pragma unroll
    for (int j = 0; j < 2; ++j){
      #pragma unroll
      for (int r = 0; r < 16; ++r){
        int rloc = row0 + i*32 + (r & 3) + 8*(r >> 2) + 4*lh;  // j-index (token)
        int cloc = col0 + j*32 + lm;                           // d / e index
        float v = acc[i][j][r];
        if (sec < 3) v = v / (1.f + __expf(-v));               // silu
        else         v = 1.f / (1.f + __expf(-v));             // sigmoid
        if (sec == 2){
          tdst[(size_t)cloc*C_ + rloc] = f2bf(v);              // v^T only
        } else {
          size_t row = (size_t)blockIdx.y*128 + rloc;
          qkvg[row*QKVG_ + (size_t)blockIdx.x*128 + cloc] = f2bf(v);
          if (sec == 1)
            tdst[(size_t)cloc*C_ + rloc] =
                f2bf(v * __expf(ld * (float)(C_ - 1 - rloc))); // dk-prescaled k^T
        }
      }
    }
  }
}

// ------------------------------------------------------ split-K partial add
__global__ __launch_bounds__(256)
void add_kernel(const float* __restrict__ p0, const float* __restrict__ p1,
                float* __restrict__ out)
{
  int i = (blockIdx.x*256 + threadIdx.x)*4;
  float4 a = *(const float4*)(p0 + i);
  float4 b = *(const float4*)(p1 + i);
  float4 o; o.x = a.x+b.x; o.y = a.y+b.y; o.z = a.z+b.z; o.w = a.w+b.w;
  *(float4*)(out + i) = o;
}

// ---------------------------------------------- per-chunk state contribution
// MsumT[ic,b,h][e][d] = sum_j vT[e][j] * kTs[d][j]. Pure MFMA, frags direct
// from global (L2-hot 32KB tiles). No LDS, no barriers.
__global__ __launch_bounds__(256)
void chunk_state_kernel(const uint16_t* __restrict__ vTg, const uint16_t* __restrict__ kTs,
                        uint16_t* __restrict__ MsumT)
{
  const int h = blockIdx.x, b = blockIdx.y, ic = blockIdx.z;
  const int t    = threadIdx.x;
  const int lane = t & 63, wave = t >> 6;
  const int wm = wave >> 1, wn = wave & 1;
  const int e0 = wm*64, d0 = wn*64;
  const int lr = lane & 15, kq = lane >> 4;
  const size_t tbase = (((size_t)b*H_ + h)*NC_ + ic)*(size_t)(HD_*C_);

  const f32x4 zero = {0.f, 0.f, 0.f, 0.f};
  f32x4 acc[4][4];
  #pragma unroll
  for (int i = 0; i < 4; ++i)
    #pragma unroll
    for (int j = 0; j < 4; ++j) acc[i][j] = zero;

  #pragma unroll
  for (int kt = 0; kt < 4; ++kt){
    bf16x8 af[4], bfr[4];
    #pragma unroll
    for (int i = 0; i < 4; ++i)
      af[i]  = *(const bf16x8*)(vTg + tbase + (size_t)(e0 + i*16 + lr)*C_ + kt*32 + kq*8);
    #pragma unroll
    for (int j = 0; j < 4; ++j)
      bfr[j] = *(const bf16x8*)(kTs + tbase + (size_t)(d0 + j*16 + lr)*C_ + kt*32 + kq*8);
    #pragma unroll
    for (int i = 0; i < 4; ++i)
      #pragma unroll
      for (int j = 0; j < 4; ++j)
        acc[i][j] = __builtin_amdgcn_mfma_f32_16x16x32_bf16(af[i], bfr[j], acc[i][j], 0, 0, 0);
  }

  uint16_t* Mout = MsumT + (((size_t)ic*B_ + b)*H_ + h)*(size_t)(HD_*HD_);
  #pragma unroll
  for (int i = 0; i < 4; ++i)
    #pragma unroll
    for (int j = 0; j < 4; ++j)
      #pragma unroll
      for (int r = 0; r < 4; ++r)
        Mout[(size_t)(e0 + i*16 + kq*4 + r)*HD_ + d0 + j*16 + lr] = f2bf(acc[i][j][r]);
}

// -------------------------------------------------- inter-chunk state scan
__global__ __launch_bounds__(256)
void scan_kernel(const uint16_t* __restrict__ MsumT, const float* __restrict__ log_decay,
                 uint16_t* __restrict__ StT)
{
  const int h = blockIdx.x, b = blockIdx.y;
  const float ld = log_decay[h];
  const float dS = __expf(ld * (float)C_);
  const int base_e = blockIdx.z*2048;
  float cur[8];
  #pragma unroll
  for (int r = 0; r < 8; ++r) cur[r] = 0.f;
  for (int i = 0; i < NC_; ++i){
    const size_t base = (((size_t)i*B_ + b)*H_ + h)*(size_t)(HD_*HD_) + base_e;
    #pragma unroll
    for (int r = 0; r < 8; ++r){
      int idx = threadIdx.x + r*256;
      StT[base + idx] = f2bf(cur[r]);
      cur[r] = cur[r]*dS + bf2f(MsumT[base + idx]);
    }
  }
}

// ------------------------------------------------------ intra-chunk attention
// o = (q@k^T ∘ Dm) @ v + dq ⊙ (q @ S_start). Phases A and B1 merged (shared
// q-frags); v-frags direct from vTg; only Ps round-trips LDS. bf16 output.
__global__ __launch_bounds__(256)
void attn_kernel(const uint16_t* __restrict__ qkvg, const uint16_t* __restrict__ vTg,
                 const uint16_t* __restrict__ StT, const float* __restrict__ log_decay,
                 uint16_t* __restrict__ o_attb)
{
  __shared__ __align__(16) uint16_t Ps[128*128];
  const int h = blockIdx.x, b = blockIdx.y, ic = blockIdx.z;
  const int t    = threadIdx.x;
  const int lane = t & 63, wave = t >> 6;
  const int wm = wave >> 1, wn = wave & 1;
  const int row0 = wm*64, col0 = wn*64;
  const int lr = lane & 15, kq = lane >> 4;
  const float ld = log_decay[h];
  const size_t rowbase = (size_t)b*N_ + (size_t)ic*C_;
  const uint16_t* qb = qkvg;
  const uint16_t* kb = qkvg + (size_t)D_;
  const uint16_t* Sb = StT + (((size_t)ic*B_ + b)*H_ + h)*(size_t)(HD_*HD_);
  const uint16_t* vb = vTg + (((size_t)b*H_ + h)*NC_ + ic)*(size_t)(HD_*C_);

  const f32x4 zero = {0.f, 0.f, 0.f, 0.f};
  f32x4 accP[4][4], accO[4][4];
  #pragma unroll
  for (int i = 0; i < 4; ++i)
    #pragma unroll
    for (int j = 0; j < 4; ++j){ accP[i][j] = zero; accO[i][j] = zero; }

  // merged phase A (P = q@k^T) + B1 (o2 = q@S_start), shared q fragments
  #pragma unroll
  for (int kt = 0; kt < 4; ++kt){
    bf16x8 af[4], bk[4], bS[4];
    #pragma unroll
    for (int i = 0; i < 4; ++i)
      af[i] = *(const bf16x8*)(qb + (rowbase + row0 + i*16 + lr)*QKVG_ + h*HD_ + kt*32 + kq*8);
    #pragma unroll
    for (int j = 0; j < 4; ++j){
      bk[j] = *(const bf16x8*)(kb + (rowbase + col0 + j*16 + lr)*QKVG_ + h*HD_ + kt*32 + kq*8);
      bS[j] = *(const bf16x8*)(Sb + (size_t)(col0 + j*16 + lr)*HD_ + kt*32 + kq*8);
    }
    #pragma unroll
    for (int i = 0; i < 4; ++i)
      #pragma unroll
      for (int j = 0; j < 4; ++j){
        accP[i][j] = __builtin_amdgcn_mfma_f32_16x16x32_bf16(af[i], bk[j], accP[i][j], 0, 0, 0);
        accO[i][j] = __builtin_amdgcn_mfma_f32_16x16x32_bf16(af[i], bS[j], accO[i][j], 0, 0, 0);
      }
  }

  // P ∘ Dm -> LDS; scale o2 rows by dq[row] = exp(ld*(row+1))
  #pragma unroll
  for (int i = 0; i < 4; ++i)
    #pragma unroll
    for (int r = 0; r < 4; ++r){
      int row = row0 + i*16 + kq*4 + r;
      float dqv = __expf(ld * (float)(row + 1));
      #pragma unroll
      for (int j = 0; j < 4; ++j){
        int col = col0 + j*16 + lr;
        int dlt = row - col;
        float f = (dlt >= 0) ? __expf(ld * (float)dlt) : 0.f;
        Ps[swz(row, col)] = f2bf(accP[i][j][r] * f);
        accO[i][j][r] *= dqv;
      }
    }

  __syncthreads();

  // phase B2: o += P @ v   (A from LDS Ps, B direct from vTg global)
  #pragma unroll
  for (int kt = 0; kt < 4; ++kt){
    bf16x8 af[4], bv[4];
    #pragma unroll
    for (int i = 0; i < 4; ++i)
      af[i] = *(const bf16x8*)(Ps + swz(row0 + i*16 + lr, kt*32 + kq*8));
    #pragma unroll
    for (int j = 0; j < 4; ++j)
      bv[j] = *(const bf16x8*)(vb + (size_t)(col0 + j*16 + lr)*C_ + kt*32 + kq*8);
    #pragma unroll
    for (int i = 0; i < 4; ++i)
      #pragma unroll
      for (int j = 0; j < 4; ++j)
        accO[i][j] = __builtin_amdgcn_mfma_f32_16x16x32_bf16(af[i], bv[j], accO[i][j], 0, 0, 0);
  }

  #pragma unroll
  for (int i = 0; i < 4; ++i)
    #pragma unroll
    for (int j = 0; j < 4; ++j)
      #pragma unroll
      for (int r = 0; r < 4; ++r){
        int row = row0 + i*16 + kq*4 + r;
        int col = col0 + j*16 + lr;
        o_attb[(rowbase + row)*D_ + h*HD_ + col] = f2bf(accO[i][j][r]);
      }
}

// --------------------------------------------- gate ⊙ + rmsnorm + cast bf16
__global__ __launch_bounds__(256)
void gate_norm_kernel(const uint16_t* __restrict__ o_attb, const uint16_t* __restrict__ qkvg,
                      const float* __restrict__ norm_w, uint16_t* __restrict__ on)
{
  const int row = blockIdx.x;
  const int t = threadIdx.x;
  const int c1 = t*4, c2 = 1024 + t*4;
  const uint16_t* orow = o_attb + (size_t)row*D_;
  const uint16_t* grow = qkvg + (size_t)row*QKVG_ + 3*D_;
  ushort4 o1 = *(const ushort4*)(orow + c1);
  ushort4 o2 = *(const ushort4*)(orow + c2);
  ushort4 g1 = *(const ushort4*)(grow + c1);
  ushort4 g2 = *(const ushort4*)(grow + c2);
  float v[8];
  v[0] = bf2f(o1.x)*bf2f(g1.x); v[1] = bf2f(o1.y)*bf2f(g1.y);
  v[2] = bf2f(o1.z)*bf2f(g1.z); v[3] = bf2f(o1.w)*bf2f(g1.w);
  v[4] = bf2f(o2.x)*bf2f(g2.x); v[5] = bf2f(o2.y)*bf2f(g2.y);
  v[6] = bf2f(o2.z)*bf2f(g2.z); v[7] = bf2f(o2.w)*bf2f(g2.w);
  float s = 0.f;
  #pragma unroll
  for (int k = 0; k < 8; ++k) s += v[k]*v[k];
  #pragma unroll
  for (int off = 32; off > 0; off >>= 1) s += __shfl_down(s, off);
  __shared__ float red[4];
  if ((t & 63) == 0) red[t >> 6] = s;
  __syncthreads();
  float total = red[0] + red[1] + red[2] + red[3];
  float scale = rsqrtf(total * (1.f/(float)D_) + 1e-6f);
  float4 w1 = *(const float4*)(norm_w + c1);
  float4 w2 = *(const float4*)(norm_w + c2);
  ushort4 b1, b2;
  b1.x = f2bf(v[0]*scale*w1.x); b1.y = f2bf(v[1]*scale*w1.y);
  b1.z = f2bf(v[2]*scale*w1.z); b1.w = f2bf(v[3]*scale*w1.w);
  b2.x = f2bf(v[4]*scale*w2.x); b2.y = f2bf(v[5]*scale*w2.y);
  b2.z = f2bf(v[6]*scale*w2.z); b2.w = f2bf(v[7]*scale*w2.w);
  *(ushort4*)(on + (size_t)row*D_ + c1) = b1;
  *(ushort4*)(on + (size_t)row*D_ + c2) = b2;
}

// =============================================================== launch
extern "C" void kernel_launch(void* const* d_in, const int* in_sizes, int n_in,
                              void* d_out, int out_size, void* d_ws, size_t ws_size,
                              hipStream_t stream) {
  const float* x         = (const float*)d_in[0];
  const float* log_decay = (const float*)d_in[1];
  const float* Wq        = (const float*)d_in[2];
  const float* Wk        = (const float*)d_in[3];
  const float* Wv        = (const float*)d_in[4];
  const float* Wo        = (const float*)d_in[5];
  const float* Wg1       = (const float*)d_in[6];
  const float* Wg2       = (const float*)d_in[7];
  const float* norm_w    = (const float*)d_in[8];
  float* out = (float*)d_out;

  // workspace layout (~185 MB with aliasing)
  uint8_t* p = (uint8_t*)d_ws;
  uint16_t* xb    = (uint16_t*)p; p += (size_t)M_*D_*2;         // reused as `on`
  uint16_t* WT    = (uint16_t*)p; p += (size_t)QKVG_*D_*2;      // reused as o_attb
  uint16_t* WoT   = (uint16_t*)p; p += (size_t)D_*D_*2;
  uint16_t* Wg1b  = (uint16_t*)p; p += (size_t)D_*HD_*2;
  uint16_t* Wg2T  = (uint16_t*)p; p += (size_t)D_*HD_*2;
  uint16_t* qkvg  = (uint16_t*)p; p += (size_t)M_*QKVG_*2;      // reused as Wo partials
  uint16_t* vTg   = (uint16_t*)p; p += (size_t)B_*H_*NC_*HD_*C_*2;
  uint16_t* kTs   = (uint16_t*)p; p += (size_t)B_*H_*NC_*HD_*C_*2;
  uint16_t* MsumT = (uint16_t*)p; p += (size_t)NC_*B_*H_*HD_*HD_*2;
  uint16_t* StT   = (uint16_t*)p; p += (size_t)NC_*B_*H_*HD_*HD_*2;
  uint16_t* o_attb= WT;               // alias: WT dead after fused GEMM
  uint16_t* on    = xb;               // alias: xb dead after fused GEMM
  float*    part  = (float*)qkvg;     // 2x32MB fp32 partials (qkvg dead by then)

  // 1. all casts + weight transposes (one launch)
  prep_all<<<dim3(64, 64, 8), 256, 0, stream>>>(Wq, Wk, Wv, Wo, Wg2, Wg1, x,
                                                WT, WoT, Wg2T, Wg1b, xb);

  // 2. Wg^T = (Wg1 @ Wg2)^T into WT slice 3
  gemm_bt2<0,1><<<dim3(D_/128, D_/128, 1), 256, 0, stream>>>(
      Wg2T, Wg1b, WT + (size_t)3*D_*D_, D_, D_, HD_, HD_);

  // 3. fused projection (q,k,gate natural; k^T·dk and v^T tiles for attention)
  gemm_qkvg<<<dim3(QKVG_/128, M_/128, 1), 256, 0, stream>>>(
      xb, WT, qkvg, vTg, kTs, log_decay);

  // 4. attention: chunk states -> scan -> intra-chunk
  chunk_state_kernel<<<dim3(H_, B_, NC_), 256, 0, stream>>>(vTg, kTs, MsumT);
  scan_kernel<<<dim3(H_, B_, 8), 256, 0, stream>>>(MsumT, log_decay, StT);
  attn_kernel<<<dim3(H_, B_, NC_), 256, 0, stream>>>(qkvg, vTg, StT, log_decay, o_attb);

  // 5. gate + rmsnorm + final projection (split-K=2)
  gate_norm_kernel<<<M_, 256, 0, stream>>>(o_attb, qkvg, norm_w, on);
  gemm_bt2<0,0><<<dim3(D_/128, M_/128, 2), 256, 0, stream>>>(
      on, WoT, part, M_, D_, D_, D_/2);
  add_kernel<<<(M_*D_)/1024, 256, 0, stream>>>(part, part + (size_t)M_*D_, out);
}

// Round 5
// 457.681 us; speedup vs baseline: 1.0259x; 1.0259x over previous
//
#include <hip/hip_runtime.h>
#include <hip/hip_bf16.h>
#include <cstdint>
#include <cstddef>

#define B_   2
#define N_   2048
#define D_   2048
#define H_   16
#define HD_  128
#define C_   128
#define NC_  16
#define M_   4096   // B_*N_
#define QKVG_ 8192  // fused projection width: q|k|v|gate (v natural slice unwritten)

typedef __attribute__((ext_vector_type(8))) short bf16x8;
typedef __attribute__((ext_vector_type(4))) float f32x4;
typedef __attribute__((ext_vector_type(16))) float f32x16;

__device__ __forceinline__ uint16_t f2bf(float f){
  __hip_bfloat16 h = __float2bfloat16(f);
  return *reinterpret_cast<uint16_t*>(&h);
}
__device__ __forceinline__ float bf2f(uint16_t u){
  union { uint32_t i; float f; } v; v.i = ((uint32_t)u) << 16; return v.f;
}

__device__ __forceinline__ void async16(const uint16_t* g, uint16_t* l){
  __builtin_amdgcn_global_load_lds(
      (const __attribute__((address_space(1))) void*)g,
      (__attribute__((address_space(3))) void*)l, 16, 0, 0);
}

// [128][128] LDS tile swizzle: 8-elem groups XORed by row nibble -> <=2-way banks
__device__ __forceinline__ int swz(int row, int c){
  return row*128 + ((((c >> 3) ^ row) & 15) << 3) + (c & 7);
}

// ---------------------------------------- all prep in ONE launch (grid.z)
// z=0..2: Wq/Wk/Wv -> WT slices; z=3: Wo -> WoT; z=4: Wg2 -> Wg2T (by<2);
// z=5: grid-stride float4 casts of x and Wg1.
__global__ __launch_bounds__(256)
void prep_all(const float* __restrict__ Wq, const float* __restrict__ Wk,
              const float* __restrict__ Wv, const float* __restrict__ Wo,
              const float* __restrict__ Wg2, const float* __restrict__ Wg1,
              const float* __restrict__ x,
              uint16_t* __restrict__ WT, uint16_t* __restrict__ WoT,
              uint16_t* __restrict__ Wg2T, uint16_t* __restrict__ Wg1b,
              uint16_t* __restrict__ xb)
{
  const int z = blockIdx.z;
  const int t = threadIdx.x;

  if (z == 5){  // straight casts, float4 -> ushort4
    const int tid = (blockIdx.y*32 + blockIdx.x)*256 + t;   // 0..262143
    #pragma unroll
    for (int i = 0; i < 8; ++i){
      size_t idx = ((size_t)tid + (size_t)i*262144)*4;      // covers 8M x elems
      float4 f = *(const float4*)(x + idx);
      ushort4 u; u.x=f2bf(f.x); u.y=f2bf(f.y); u.z=f2bf(f.z); u.w=f2bf(f.w);
      *(ushort4*)(xb + idx) = u;
    }
    if (tid < 65536){                                       // 256K Wg1 elems
      size_t idx = (size_t)tid*4;
      float4 f = *(const float4*)(Wg1 + idx);
      ushort4 u; u.x=f2bf(f.x); u.y=f2bf(f.y); u.z=f2bf(f.z); u.w=f2bf(f.w);
      *(ushort4*)(Wg1b + idx) = u;
    }
    return;
  }

  // 64x64 transpose-cast tiles
  const float* src; uint16_t* dst; int R, Cc;
  if (z < 3)      { src = (z==0)?Wq:(z==1)?Wk:Wv; dst = WT + (size_t)z*D_*D_; R = D_; Cc = D_; }
  else if (z == 3){ src = Wo;  dst = WoT;  R = D_;  Cc = D_; }
  else            { if (blockIdx.y >= 2) return;
                    src = Wg2; dst = Wg2T; R = HD_; Cc = D_; }

  __shared__ uint16_t tile[64][68];
  const int r0 = blockIdx.y*64, c0 = blockIdx.x*64;
  const int tr = t >> 4;          // 0..15
  const int tc = (t & 15)*4;
  #pragma unroll
  for (int p = 0; p < 4; ++p){
    int r = p*16 + tr;
    float4 f = *(const float4*)(src + (size_t)(r0 + r)*Cc + c0 + tc);
    ushort4 u; u.x=f2bf(f.x); u.y=f2bf(f.y); u.z=f2bf(f.z); u.w=f2bf(f.w);
    *(ushort4*)(&tile[r][tc]) = u;
  }
  __syncthreads();
  #pragma unroll
  for (int p = 0; p < 4; ++p){
    int oc = p*16 + tr;           // transposed row = original col
    ushort4 u;
    u.x = tile[tc+0][oc]; u.y = tile[tc+1][oc];
    u.z = tile[tc+2][oc]; u.w = tile[tc+3][oc];
    *(ushort4*)(dst + (size_t)(c0 + oc)*R + r0 + tc) = u;
  }
}

// ------------------------------------------------- generic GEMM: BK=64, 32x32x16
// C = act(A @ Bt^T). blockIdx.z = split-K slice (fp32 partials for OUTBF=0).
template<int ACT, int OUTBF>
__global__ __launch_bounds__(256)
void gemm_bt2(const uint16_t* __restrict__ A, const uint16_t* __restrict__ Bt,
              void* __restrict__ Cout, int M, int Ncols, int K, int klen)
{
  __shared__ __align__(16) uint16_t As[128*64];
  __shared__ __align__(16) uint16_t Bs[128*64];
  const int t    = threadIdx.x;
  const int lane = t & 63, wave = t >> 6;
  const int wm = wave >> 1, wn = wave & 1;
  const int row0 = wm*64, col0 = wn*64;
  const int lm = lane & 31, lh = lane >> 5;

  const uint16_t* Ap = A  + (size_t)(blockIdx.y*128)*K;
  const uint16_t* Bp = Bt + (size_t)(blockIdx.x*128)*K;
  const int kbeg = blockIdx.z * klen;

  f32x16 acc[2][2];
  #pragma unroll
  for (int i = 0; i < 2; ++i)
    #pragma unroll
    for (int j = 0; j < 2; ++j)
      #pragma unroll
      for (int r = 0; r < 16; ++r) acc[i][j][r] = 0.f;

  const int srow = t >> 3;
  const int gch  = (t & 7) ^ (srow & 7);
  const size_t aoff0 = (size_t)srow*K + gch*8;

  for (int k0 = kbeg; k0 < kbeg + klen; k0 += 64){
    #pragma unroll
    for (int c = 0; c < 4; ++c){
      async16(Ap + (size_t)(c*32)*K + aoff0 + k0, As + c*2048 + t*8);
      async16(Bp + (size_t)(c*32)*K + aoff0 + k0, Bs + c*2048 + t*8);
    }
    __syncthreads();
    #pragma unroll
    for (int kh = 0; kh < 4; ++kh){
      bf16x8 af[2], bfr[2];
      const int ch = kh*2 + lh;
      #pragma unroll
      for (int i = 0; i < 2; ++i){
        int r = row0 + i*32 + lm;
        af[i] = *(const bf16x8*)(As + r*64 + ((ch ^ (r & 7)) << 3));
      }
      #pragma unroll
      for (int j = 0; j < 2; ++j){
        int r = col0 + j*32 + lm;
        bfr[j] = *(const bf16x8*)(Bs + r*64 + ((ch ^ (r & 7)) << 3));
      }
      #pragma unroll
      for (int i = 0; i < 2; ++i)
        #pragma unroll
        for (int j = 0; j < 2; ++j)
          acc[i][j] = __builtin_amdgcn_mfma_f32_32x32x16_bf16(af[i], bfr[j], acc[i][j], 0, 0, 0);
    }
    __syncthreads();
  }

  uint16_t* outb = (uint16_t*)Cout;
  float*    outf = (float*)Cout + (OUTBF ? 0 : (size_t)blockIdx.z*M*Ncols);
  #pragma unroll
  for (int i = 0; i < 2; ++i){
    #pragma unroll
    for (int j = 0; j < 2; ++j){
      #pragma unroll
      for (int r = 0; r < 16; ++r){
        int row = blockIdx.y*128 + row0 + i*32 + (r & 3) + 8*(r >> 2) + 4*lh;
        int col = blockIdx.x*128 + col0 + j*32 + lm;
        float v = acc[i][j][r];
        if (ACT == 1)      v = v / (1.f + __expf(-v));
        else if (ACT == 2) v = 1.f / (1.f + __expf(-v));
        size_t off = (size_t)row*Ncols + col;
        if (OUTBF) outb[off] = f2bf(v);
        else       outf[off] = v;
      }
    }
  }
}

// ------------------------------------- fused q|k|v|gate projection
// sections (blockIdx.x>>4): 0=q natural silu; 1=k natural silu + dk-scaled k^T
// (via LDS re-tile, coalesced); 2=v ONLY as v^T (LDS re-tile, coalesced);
// 3=gate natural sigmoid. Each k/v col-block covers exactly one (b,h,ic) tile.
__global__ __launch_bounds__(256)
void gemm_qkvg(const uint16_t* __restrict__ A, const uint16_t* __restrict__ Bt,
               uint16_t* __restrict__ qkvg, uint16_t* __restrict__ vTg,
               uint16_t* __restrict__ kTs, const float* __restrict__ log_decay)
{
  const int K = D_;
  __shared__ __align__(16) uint16_t smem[128*128];   // As | Bs, reused as T
  uint16_t* As = smem;
  uint16_t* Bs = smem + 128*64;
  const int t    = threadIdx.x;
  const int lane = t & 63, wave = t >> 6;
  const int wm = wave >> 1, wn = wave & 1;
  const int row0 = wm*64, col0 = wn*64;
  const int lm = lane & 31, lh = lane >> 5;

  const uint16_t* Ap = A  + (size_t)(blockIdx.y*128)*K;
  const uint16_t* Bp = Bt + (size_t)(blockIdx.x*128)*K;

  f32x16 acc[2][2];
  #pragma unroll
  for (int i = 0; i < 2; ++i)
    #pragma unroll
    for (int j = 0; j < 2; ++j)
      #pragma unroll
      for (int r = 0; r < 16; ++r) acc[i][j][r] = 0.f;

  const int srow = t >> 3;
  const int gch  = (t & 7) ^ (srow & 7);
  const size_t aoff0 = (size_t)srow*K + gch*8;

  for (int k0 = 0; k0 < K; k0 += 64){
    #pragma unroll
    for (int c = 0; c < 4; ++c){
      async16(Ap + (size_t)(c*32)*K + aoff0 + k0, As + c*2048 + t*8);
      async16(Bp + (size_t)(c*32)*K + aoff0 + k0, Bs + c*2048 + t*8);
    }
    __syncthreads();
    #pragma unroll
    for (int kh = 0; kh < 4; ++kh){
      bf16x8 af[2], bfr[2];
      const int ch = kh*2 + lh;
      #pragma unroll
      for (int i = 0; i < 2; ++i){
        int r = row0 + i*32 + lm;
        af[i] = *(const bf16x8*)(As + r*64 + ((ch ^ (r & 7)) << 3));
      }
      #pragma unroll
      for (int j = 0; j < 2; ++j){
        int r = col0 + j*32 + lm;
        bfr[j] = *(const bf16x8*)(Bs + r*64 + ((ch ^ (r & 7)) << 3));
      }
      #pragma unroll
      for (int i = 0; i < 2; ++i)
        #pragma unroll
        for (int j = 0; j < 2; ++j)
          acc[i][j] = __builtin_amdgcn_mfma_f32_32x32x16_bf16(af[i], bfr[j], acc[i][j], 0, 0, 0);
    }
    __syncthreads();   // last iteration: also drains As/Bs for the T re-tile
  }

  const int sec = blockIdx.x >> 4;        // 0 q, 1 k, 2 v, 3 gate
  const int h   = blockIdx.x & 15;
  const float ld = log_decay[h];

  // activation + natural store (q, k, gate) + transposed LDS tile (k, v)
  #pragma unroll
  for (int i = 0; i < 2; ++i){
    #pragma unroll
    for (int j = 0; j < 2; ++j){
      #pragma unroll
      for (int r = 0; r < 16; ++r){
        int rloc = row0 + i*32 + (r & 3) + 8*(r >> 2) + 4*lh;   // token within chunk
        int cloc = col0 + j*32 + lm;                            // d / e index
        float v = acc[i][j][r];
        if (sec == 3) v = 1.f / (1.f + __expf(-v));             // sigmoid
        else          v = v / (1.f + __expf(-v));               // silu
        if (sec != 2){
          size_t row = (size_t)blockIdx.y*128 + rloc;
          qkvg[row*QKVG_ + (size_t)blockIdx.x*128 + cloc] = f2bf(v);
        }
        if (sec == 1 || sec == 2){
          float tv = (sec == 1) ? v * __expf(ld * (float)(C_ - 1 - rloc)) : v;
          smem[swz(cloc, rloc)] = f2bf(tv);   // T[e][j], swizzled
        }
      }
    }
  }

  if (sec == 1 || sec == 2){
    __syncthreads();
    const int bb = blockIdx.y >> 4;
    const int ic = blockIdx.y & 15;
    uint16_t* tdst = (sec == 2 ? vTg : kTs) +
                     (((size_t)bb*H_ + h)*NC_ + ic)*(size_t)(HD_*C_);
    const int e0 = t >> 4;          // + k*16
    const int j0 = (t & 15)*8;
    #pragma unroll
    for (int k = 0; k < 8; ++k){
      int e = e0 + k*16;
      bf16x8 val = *(const bf16x8*)(smem + swz(e, j0));
      *(bf16x8*)(tdst + (size_t)e*C_ + j0) = val;  // 16 lanes = one 256B row
    }
  }
}

// ------------------------------------------------------ split-K partial add
__global__ __launch_bounds__(256)
void add_kernel(const float* __restrict__ p0, const float* __restrict__ p1,
                float* __restrict__ out)
{
  int i = (blockIdx.x*256 + threadIdx.x)*4;
  float4 a = *(const float4*)(p0 + i);
  float4 b = *(const float4*)(p1 + i);
  float4 o; o.x = a.x+b.x; o.y = a.y+b.y; o.z = a.z+b.z; o.w = a.w+b.w;
  *(float4*)(out + i) = o;
}

// ---------------------------------------------- per-chunk state contribution
// MsumT[ic,b,h][e][d] = sum_j vT[e][j] * kTs[d][j]. Pure MFMA, no LDS.
__global__ __launch_bounds__(256)
void chunk_state_kernel(const uint16_t* __restrict__ vTg, const uint16_t* __restrict__ kTs,
                        uint16_t* __restrict__ MsumT)
{
  const int h = blockIdx.x, b = blockIdx.y, ic = blockIdx.z;
  const int t    = threadIdx.x;
  const int lane = t & 63, wave = t >> 6;
  const int wm = wave >> 1, wn = wave & 1;
  const int e0 = wm*64, d0 = wn*64;
  const int lr = lane & 15, kq = lane >> 4;
  const size_t tbase = (((size_t)b*H_ + h)*NC_ + ic)*(size_t)(HD_*C_);

  const f32x4 zero = {0.f, 0.f, 0.f, 0.f};
  f32x4 acc[4][4];
  #pragma unroll
  for (int i = 0; i < 4; ++i)
    #pragma unroll
    for (int j = 0; j < 4; ++j) acc[i][j] = zero;

  #pragma unroll
  for (int kt = 0; kt < 4; ++kt){
    bf16x8 af[4], bfr[4];
    #pragma unroll
    for (int i = 0; i < 4; ++i)
      af[i]  = *(const bf16x8*)(vTg + tbase + (size_t)(e0 + i*16 + lr)*C_ + kt*32 + kq*8);
    #pragma unroll
    for (int j = 0; j < 4; ++j)
      bfr[j] = *(const bf16x8*)(kTs + tbase + (size_t)(d0 + j*16 + lr)*C_ + kt*32 + kq*8);
    #pragma unroll
    for (int i = 0; i < 4; ++i)
      #pragma unroll
      for (int j = 0; j < 4; ++j)
        acc[i][j] = __builtin_amdgcn_mfma_f32_16x16x32_bf16(af[i], bfr[j], acc[i][j], 0, 0, 0);
  }

  uint16_t* Mout = MsumT + (((size_t)ic*B_ + b)*H_ + h)*(size_t)(HD_*HD_);
  #pragma unroll
  for (int i = 0; i < 4; ++i)
    #pragma unroll
    for (int j = 0; j < 4; ++j)
      #pragma unroll
      for (int r = 0; r < 4; ++r)
        Mout[(size_t)(e0 + i*16 + kq*4 + r)*HD_ + d0 + j*16 + lr] = f2bf(acc[i][j][r]);
}

// -------------------------------------------------- inter-chunk state scan
__global__ __launch_bounds__(256)
void scan_kernel(const uint16_t* __restrict__ MsumT, const float* __restrict__ log_decay,
                 uint16_t* __restrict__ StT)
{
  const int h = blockIdx.x, b = blockIdx.y;
  const float ld = log_decay[h];
  const float dS = __expf(ld * (float)C_);
  const int base_e = blockIdx.z*2048;
  float cur[8];
  #pragma unroll
  for (int r = 0; r < 8; ++r) cur[r] = 0.f;
  for (int i = 0; i < NC_; ++i){
    const size_t base = (((size_t)i*B_ + b)*H_ + h)*(size_t)(HD_*HD_) + base_e;
    #pragma unroll
    for (int r = 0; r < 8; ++r){
      int idx = threadIdx.x + r*256;
      StT[base + idx] = f2bf(cur[r]);
      cur[r] = cur[r]*dS + bf2f(MsumT[base + idx]);
    }
  }
}

// ------------------------------------------------------ intra-chunk attention
// o = (q@k^T ∘ Dm) @ v + dq ⊙ (q @ S_start). Merged A+B1 (shared q frags);
// v frags direct from vTg; Ps through LDS; bf16 output.
__global__ __launch_bounds__(256)
void attn_kernel(const uint16_t* __restrict__ qkvg, const uint16_t* __restrict__ vTg,
                 const uint16_t* __restrict__ StT, const float* __restrict__ log_decay,
                 uint16_t* __restrict__ o_attb)
{
  __shared__ __align__(16) uint16_t Ps[128*128];
  const int h = blockIdx.x, b = blockIdx.y, ic = blockIdx.z;
  const int t    = threadIdx.x;
  const int lane = t & 63, wave = t >> 6;
  const int wm = wave >> 1, wn = wave & 1;
  const int row0 = wm*64, col0 = wn*64;
  const int lr = lane & 15, kq = lane >> 4;
  const float ld = log_decay[h];
  const size_t rowbase = (size_t)b*N_ + (size_t)ic*C_;
  const uint16_t* qb = qkvg;
  const uint16_t* kb = qkvg + (size_t)D_;
  const uint16_t* Sb = StT + (((size_t)ic*B_ + b)*H_ + h)*(size_t)(HD_*HD_);
  const uint16_t* vb = vTg + (((size_t)b*H_ + h)*NC_ + ic)*(size_t)(HD_*C_);

  const f32x4 zero = {0.f, 0.f, 0.f, 0.f};
  f32x4 accP[4][4], accO[4][4];
  #pragma unroll
  for (int i = 0; i < 4; ++i)
    #pragma unroll
    for (int j = 0; j < 4; ++j){ accP[i][j] = zero; accO[i][j] = zero; }

  #pragma unroll
  for (int kt = 0; kt < 4; ++kt){
    bf16x8 af[4], bk[4], bS[4];
    #pragma unroll
    for (int i = 0; i < 4; ++i)
      af[i] = *(const bf16x8*)(qb + (rowbase + row0 + i*16 + lr)*QKVG_ + h*HD_ + kt*32 + kq*8);
    #pragma unroll
    for (int j = 0; j < 4; ++j){
      bk[j] = *(const bf16x8*)(kb + (rowbase + col0 + j*16 + lr)*QKVG_ + h*HD_ + kt*32 + kq*8);
      bS[j] = *(const bf16x8*)(Sb + (size_t)(col0 + j*16 + lr)*HD_ + kt*32 + kq*8);
    }
    #pragma unroll
    for (int i = 0; i < 4; ++i)
      #pragma unroll
      for (int j = 0; j < 4; ++j){
        accP[i][j] = __builtin_amdgcn_mfma_f32_16x16x32_bf16(af[i], bk[j], accP[i][j], 0, 0, 0);
        accO[i][j] = __builtin_amdgcn_mfma_f32_16x16x32_bf16(af[i], bS[j], accO[i][j], 0, 0, 0);
      }
  }

  #pragma unroll
  for (int i = 0; i < 4; ++i)
    #pragma unroll
    for (int r = 0; r < 4; ++r){
      int row = row0 + i*16 + kq*4 + r;
      float dqv = __expf(ld * (float)(row + 1));
      #pragma unroll
      for (int j = 0; j < 4; ++j){
        int col = col0 + j*16 + lr;
        int dlt = row - col;
        float f = (dlt >= 0) ? __expf(ld * (float)dlt) : 0.f;
        Ps[swz(row, col)] = f2bf(accP[i][j][r] * f);
        accO[i][j][r] *= dqv;
      }
    }

  __syncthreads();

  #pragma unroll
  for (int kt = 0; kt < 4; ++kt){
    bf16x8 af[4], bv[4];
    #pragma unroll
    for (int i = 0; i < 4; ++i)
      af[i] = *(const bf16x8*)(Ps + swz(row0 + i*16 + lr, kt*32 + kq*8));
    #pragma unroll
    for (int j = 0; j < 4; ++j)
      bv[j] = *(const bf16x8*)(vb + (size_t)(col0 + j*16 + lr)*C_ + kt*32 + kq*8);
    #pragma unroll
    for (int i = 0; i < 4; ++i)
      #pragma unroll
      for (int j = 0; j < 4; ++j)
        accO[i][j] = __builtin_amdgcn_mfma_f32_16x16x32_bf16(af[i], bv[j], accO[i][j], 0, 0, 0);
  }

  #pragma unroll
  for (int i = 0; i < 4; ++i)
    #pragma unroll
    for (int j = 0; j < 4; ++j)
      #pragma unroll
      for (int r = 0; r < 4; ++r){
        int row = row0 + i*16 + kq*4 + r;
        int col = col0 + j*16 + lr;
        o_attb[(rowbase + row)*D_ + h*HD_ + col] = f2bf(accO[i][j][r]);
      }
}

// --------------------------------------------- gate ⊙ + rmsnorm + cast bf16
__global__ __launch_bounds__(256)
void gate_norm_kernel(const uint16_t* __restrict__ o_attb, const uint16_t* __restrict__ qkvg,
                      const float* __restrict__ norm_w, uint16_t* __restrict__ on)
{
  const int row = blockIdx.x;
  const int t = threadIdx.x;
  const int c1 = t*4, c2 = 1024 + t*4;
  const uint16_t* orow = o_attb + (size_t)row*D_;
  const uint16_t* grow = qkvg + (size_t)row*QKVG_ + 3*D_;
  ushort4 o1 = *(const ushort4*)(orow + c1);
  ushort4 o2 = *(const ushort4*)(orow + c2);
  ushort4 g1 = *(const ushort4*)(grow + c1);
  ushort4 g2 = *(const ushort4*)(grow + c2);
  float v[8];
  v[0] = bf2f(o1.x)*bf2f(g1.x); v[1] = bf2f(o1.y)*bf2f(g1.y);
  v[2] = bf2f(o1.z)*bf2f(g1.z); v[3] = bf2f(o1.w)*bf2f(g1.w);
  v[4] = bf2f(o2.x)*bf2f(g2.x); v[5] = bf2f(o2.y)*bf2f(g2.y);
  v[6] = bf2f(o2.z)*bf2f(g2.z); v[7] = bf2f(o2.w)*bf2f(g2.w);
  float s = 0.f;
  #pragma unroll
  for (int k = 0; k < 8; ++k) s += v[k]*v[k];
  #pragma unroll
  for (int off = 32; off > 0; off >>= 1) s += __shfl_down(s, off);
  __shared__ float red[4];
  if ((t & 63) == 0) red[t >> 6] = s;
  __syncthreads();
  float total = red[0] + red[1] + red[2] + red[3];
  float scale = rsqrtf(total * (1.f/(float)D_) + 1e-6f);
  float4 w1 = *(const float4*)(norm_w + c1);
  float4 w2 = *(const float4*)(norm_w + c2);
  ushort4 b1, b2;
  b1.x = f2bf(v[0]*scale*w1.x); b1.y = f2bf(v[1]*scale*w1.y);
  b1.z = f2bf(v[2]*scale*w1.z); b1.w = f2bf(v[3]*scale*w1.w);
  b2.x = f2bf(v[4]*scale*w2.x); b2.y = f2bf(v[5]*scale*w2.y);
  b2.z = f2bf(v[6]*scale*w2.z); b2.w = f2bf(v[7]*scale*w2.w);
  *(ushort4*)(on + (size_t)row*D_ + c1) = b1;
  *(ushort4*)(on + (size_t)row*D_ + c2) = b2;
}

// =============================================================== launch
extern "C" void kernel_launch(void* const* d_in, const int* in_sizes, int n_in,
                              void* d_out, int out_size, void* d_ws, size_t ws_size,
                              hipStream_t stream) {
  const float* x         = (const float*)d_in[0];
  const float* log_decay = (const float*)d_in[1];
  const float* Wq        = (const float*)d_in[2];
  const float* Wk        = (const float*)d_in[3];
  const float* Wv        = (const float*)d_in[4];
  const float* Wo        = (const float*)d_in[5];
  const float* Wg1       = (const float*)d_in[6];
  const float* Wg2       = (const float*)d_in[7];
  const float* norm_w    = (const float*)d_in[8];
  float* out = (float*)d_out;

  // workspace layout (~185 MB with aliasing)
  uint8_t* p = (uint8_t*)d_ws;
  uint16_t* xb    = (uint16_t*)p; p += (size_t)M_*D_*2;         // reused as `on`
  uint16_t* WT    = (uint16_t*)p; p += (size_t)QKVG_*D_*2;      // reused as o_attb
  uint16_t* WoT   = (uint16_t*)p; p += (size_t)D_*D_*2;
  uint16_t* Wg1b  = (uint16_t*)p; p += (size_t)D_*HD_*2;
  uint16_t* Wg2T  = (uint16_t*)p; p += (size_t)D_*HD_*2;
  uint16_t* qkvg  = (uint16_t*)p; p += (size_t)M_*QKVG_*2;      // reused as Wo partials
  uint16_t* vTg   = (uint16_t*)p; p += (size_t)B_*H_*NC_*HD_*C_*2;
  uint16_t* kTs   = (uint16_t*)p; p += (size_t)B_*H_*NC_*HD_*C_*2;
  uint16_t* MsumT = (uint16_t*)p; p += (size_t)NC_*B_*H_*HD_*HD_*2;
  uint16_t* StT   = (uint16_t*)p; p += (size_t)NC_*B_*H_*HD_*HD_*2;
  uint16_t* o_attb= WT;               // alias: WT dead after fused GEMM
  uint16_t* on    = xb;               // alias: xb dead after fused GEMM
  float*    part  = (float*)qkvg;     // 2x32MB fp32 partials

  // 1. all casts + weight transposes (one launch)
  prep_all<<<dim3(32, 32, 6), 256, 0, stream>>>(Wq, Wk, Wv, Wo, Wg2, Wg1, x,
                                                WT, WoT, Wg2T, Wg1b, xb);

  // 2. Wg^T = (Wg1 @ Wg2)^T into WT slice 3
  gemm_bt2<0,1><<<dim3(D_/128, D_/128, 1), 256, 0, stream>>>(
      Wg2T, Wg1b, WT + (size_t)3*D_*D_, D_, D_, HD_, HD_);

  // 3. fused projection (q,k,gate natural; k^T·dk, v^T coalesced via LDS re-tile)
  gemm_qkvg<<<dim3(QKVG_/128, M_/128, 1), 256, 0, stream>>>(
      xb, WT, qkvg, vTg, kTs, log_decay);

  // 4. attention: chunk states -> scan -> intra-chunk
  chunk_state_kernel<<<dim3(H_, B_, NC_), 256, 0, stream>>>(vTg, kTs, MsumT);
  scan_kernel<<<dim3(H_, B_, 8), 256, 0, stream>>>(MsumT, log_decay, StT);
  attn_kernel<<<dim3(H_, B_, NC_), 256, 0, stream>>>(qkvg, vTg, StT, log_decay, o_attb);

  // 5. gate + rmsnorm + final projection (split-K=2)
  gate_norm_kernel<<<M_, 256, 0, stream>>>(o_attb, qkvg, norm_w, on);
  gemm_bt2<0,0><<<dim3(D_/128, M_/128, 2), 256, 0, stream>>>(
      on, WoT, part, M_, D_, D_, D_/2);
  add_kernel<<<(M_*D_)/1024, 256, 0, stream>>>(part, part + (size_t)M_*D_, out);
}